// Round 11
// baseline (128.825 us; speedup 1.0000x reference)
//
#include <hip/hip_runtime.h>

#define DIN 128
#define DOUT 64
#define NEG_SLOPE 0.2f
#define ALPHA 0.5f
#define NBUK 1024   // coarse buckets: bucket = seg >> 7, covers 2n = 100000 segments
#define EPB  2048   // edges per block in binning passes (391 blocks)

typedef __attribute__((ext_vector_type(8))) short bf16x8;
typedef __attribute__((ext_vector_type(4))) float f32x4;

__device__ __forceinline__ float lrelu(float x) { return x > 0.0f ? x : NEG_SLOPE * x; }

__device__ __forceinline__ unsigned short f2bf(float f) {
    unsigned u = __float_as_uint(f);
    unsigned r = (u + 0x7fffu + ((u >> 16) & 1u)) >> 16;
    return (unsigned short)r;
}
__device__ __forceinline__ float bf2f(unsigned short h) {
    return __uint_as_float((unsigned)h << 16);
}
__device__ __forceinline__ float bfu_lo(unsigned u) { return __uint_as_float(u << 16); }
__device__ __forceinline__ float bfu_hi(unsigned u) { return __uint_as_float(u & 0xffff0000u); }
__device__ __forceinline__ float readlane_f(float v, int l) {
    return __int_as_float(__builtin_amdgcn_readlane(__float_as_int(v), l));
}

// ---------------- wfrag: bake W1,W2 into MFMA B-fragment order, split hi/lo.
// One block per (mat,kk,t) combo: 32 blocks x 64 lanes.
__global__ __launch_bounds__(64) void wfrag_kernel(
    const float* __restrict__ W1, const float* __restrict__ W2,
    unsigned short* __restrict__ wf)
{
    int combo = blockIdx.x;          // [0,32)
    int mat = combo >> 4;
    int kk = (combo >> 2) & 3;
    int t = combo & 3;
    int l = threadIdx.x;
    int g = l >> 4, c = l & 15;
    const float* W = mat ? W2 : W1;
    #pragma unroll
    for (int j = 0; j < 8; ++j) {
        float w = W[(kk * 32 + g * 8 + j) * DOUT + t * 16 + c];
        unsigned short hi = f2bf(w);
        unsigned short lo = f2bf(w - bf2f(hi));
        wf[(size_t)(((mat * 2 + 0) * 16 + kk * 4 + t) * 512) + l * 8 + j] = hi;
        wf[(size_t)(((mat * 2 + 1) * 16 + kk * 4 + t) * 512) + l * 8 + j] = lo;
    }
}

// ---------------- proj via MFMA: one wave per 16-node tile, no LDS.
__global__ __launch_bounds__(256) void proj_kernel(
    const float* __restrict__ x, const unsigned short* __restrict__ wf,
    const float* __restrict__ as1, const float* __restrict__ ad1,
    const float* __restrict__ as2, const float* __restrict__ ad2,
    unsigned short* __restrict__ xw1, unsigned short* __restrict__ xw2,
    float* __restrict__ s1, float* __restrict__ d1,
    float* __restrict__ s2, float* __restrict__ d2, int n)
{
    int ntiles = (n + 15) >> 4;
    int tile = blockIdx.x * 4 + (threadIdx.x >> 6);
    if (tile >= ntiles) return;
    int l = threadIdx.x & 63;
    int g = l >> 4, c = l & 15;

    int arow = tile * 16 + c;
    if (arow >= n) arow = n - 1;   // clamp: stores are guarded

    bf16x8 ahi[4], alo[4];
    const float* xr = x + (size_t)arow * DIN + g * 8;
    #pragma unroll
    for (int kk = 0; kk < 4; ++kk) {
        float4 v0 = *(const float4*)(xr + kk * 32);
        float4 v1 = *(const float4*)(xr + kk * 32 + 4);
        float xv[8] = {v0.x, v0.y, v0.z, v0.w, v1.x, v1.y, v1.z, v1.w};
        #pragma unroll
        for (int j = 0; j < 8; ++j) {
            unsigned short hi = f2bf(xv[j]);
            unsigned short lo = f2bf(xv[j] - bf2f(hi));
            ahi[kk][j] = (short)hi;
            alo[kk][j] = (short)lo;
        }
    }

    float vs1[4] = {0, 0, 0, 0}, vd1[4] = {0, 0, 0, 0};
    float vs2[4] = {0, 0, 0, 0}, vd2[4] = {0, 0, 0, 0};
    const bf16x8* wfv = (const bf16x8*)wf;

    #pragma unroll
    for (int t = 0; t < 4; ++t) {
        f32x4 C1 = {0.f, 0.f, 0.f, 0.f}, C2 = {0.f, 0.f, 0.f, 0.f};
        #pragma unroll
        for (int kk = 0; kk < 4; ++kk) {
            bf16x8 bh1 = wfv[(size_t)((0 * 16 + kk * 4 + t) * 64) + l];
            bf16x8 bl1 = wfv[(size_t)((1 * 16 + kk * 4 + t) * 64) + l];
            bf16x8 bh2 = wfv[(size_t)((2 * 16 + kk * 4 + t) * 64) + l];
            bf16x8 bl2 = wfv[(size_t)((3 * 16 + kk * 4 + t) * 64) + l];
            C1 = __builtin_amdgcn_mfma_f32_16x16x32_bf16(ahi[kk], bh1, C1, 0, 0, 0);
            C1 = __builtin_amdgcn_mfma_f32_16x16x32_bf16(alo[kk], bh1, C1, 0, 0, 0);
            C1 = __builtin_amdgcn_mfma_f32_16x16x32_bf16(ahi[kk], bl1, C1, 0, 0, 0);
            C2 = __builtin_amdgcn_mfma_f32_16x16x32_bf16(ahi[kk], bh2, C2, 0, 0, 0);
            C2 = __builtin_amdgcn_mfma_f32_16x16x32_bf16(alo[kk], bh2, C2, 0, 0, 0);
            C2 = __builtin_amdgcn_mfma_f32_16x16x32_bf16(ahi[kk], bl2, C2, 0, 0, 0);
        }
        float a1v = as1[t * 16 + c], a2v = ad1[t * 16 + c];
        float a3v = as2[t * 16 + c], a4v = ad2[t * 16 + c];
        #pragma unroll
        for (int r = 0; r < 4; ++r) {
            vs1[r] = fmaf(C1[r], a1v, vs1[r]);
            vd1[r] = fmaf(C1[r], a2v, vd1[r]);
            vs2[r] = fmaf(C2[r], a3v, vs2[r]);
            vd2[r] = fmaf(C2[r], a4v, vd2[r]);
        }
        #pragma unroll
        for (int r = 0; r < 4; ++r) {
            int node = tile * 16 + g * 4 + r;
            if (node < n) {
                xw1[(size_t)node * DOUT + t * 16 + c] = f2bf(C1[r]);
                xw2[(size_t)node * DOUT + t * 16 + c] = f2bf(C2[r]);
            }
        }
    }
    #pragma unroll
    for (int off = 1; off < 16; off <<= 1) {
        #pragma unroll
        for (int r = 0; r < 4; ++r) {
            vs1[r] += __shfl_xor(vs1[r], off);
            vd1[r] += __shfl_xor(vd1[r], off);
            vs2[r] += __shfl_xor(vs2[r], off);
            vd2[r] += __shfl_xor(vd2[r], off);
        }
    }
    if (c == 0) {
        #pragma unroll
        for (int r = 0; r < 4; ++r) {
            int node = tile * 16 + g * 4 + r;
            if (node < n) {
                s1[node] = vs1[r]; d1[node] = vd1[r];
                s2[node] = vs2[r]; d2[node] = vd2[r];
            }
        }
    }
}

// ---------------- pass A1: per-block bucket histogram (no global atomics)
__global__ __launch_bounds__(256) void binhist_kernel(
    const int* __restrict__ src, const int* __restrict__ dst,
    int* __restrict__ hist, int e, int n, int nblk)
{
    __shared__ int cnt[NBUK];
    int tid = threadIdx.x, blk = blockIdx.x;
    for (int b = tid; b < NBUK; b += 256) cnt[b] = 0;
    __syncthreads();
    int base = blk * EPB;
    for (int k = 0; k < EPB / 256; ++k) {
        int t = base + k * 256 + tid;
        if (t < e) {
            int s = src[t], d = dst[t];
            atomicAdd(&cnt[d >> 7], 1);
            atomicAdd(&cnt[(n + s) >> 7], 1);
        }
    }
    __syncthreads();
    for (int b = tid; b < NBUK; b += 256)
        hist[(size_t)b * nblk + blk] = cnt[b];
}

// ---------------- scan chain
__global__ __launch_bounds__(256) void scan_part_kernel(
    const int* __restrict__ deg, int* __restrict__ part, int n2)
{
    __shared__ int sm[256];
    int b = blockIdx.x, t = threadIdx.x;
    int base = b * 1024 + t * 4;
    int s = 0;
    #pragma unroll
    for (int k = 0; k < 4; ++k) { int i = base + k; if (i < n2) s += deg[i]; }
    sm[t] = s; __syncthreads();
    for (int o = 128; o; o >>= 1) { if (t < o) sm[t] += sm[t + o]; __syncthreads(); }
    if (t == 0) part[b] = sm[0];
}

__global__ __launch_bounds__(1024) void scan_mid_kernel(
    int* __restrict__ part, int nb, int* __restrict__ offs, int n2, int total)
{
    __shared__ int sm[1024];
    int t = threadIdx.x;
    int v = (t < nb) ? part[t] : 0;
    sm[t] = v; __syncthreads();
    for (int o = 1; o < 1024; o <<= 1) {
        int u = (t >= o) ? sm[t - o] : 0;
        __syncthreads();
        sm[t] += u;
        __syncthreads();
    }
    if (t < nb) part[t] = sm[t] - v;
    if (t == 0) offs[n2] = total;
}

__global__ __launch_bounds__(256) void scan_apply_kernel(
    const int* __restrict__ deg, const int* __restrict__ part,
    int* __restrict__ offs, int n2)
{
    __shared__ int sm[256];
    int b = blockIdx.x, t = threadIdx.x;
    int base = b * 1024 + t * 4;
    int d[4]; int s = 0;
    #pragma unroll
    for (int k = 0; k < 4; ++k) { int i = base + k; d[k] = (i < n2) ? deg[i] : 0; s += d[k]; }
    sm[t] = s; __syncthreads();
    for (int o = 1; o < 256; o <<= 1) {
        int u = (t >= o) ? sm[t - o] : 0;
        __syncthreads();
        sm[t] += u;
        __syncthreads();
    }
    int run = part[b] + sm[t] - s;
    #pragma unroll
    for (int k = 0; k < 4; ++k) {
        int i = base + k;
        if (i < n2) { offs[i] = run; run += d[k]; }
    }
}

// ---------------- pass A3: bin edges into per-(block,bucket) private chunks.
__global__ __launch_bounds__(256) void binscatter_kernel(
    const int* __restrict__ src, const int* __restrict__ dst,
    const int* __restrict__ hscan, unsigned* __restrict__ staging,
    int e, int n, int nblk)
{
    __shared__ int cur[NBUK];
    int tid = threadIdx.x, blk = blockIdx.x;
    for (int b = tid; b < NBUK; b += 256)
        cur[b] = hscan[(size_t)b * nblk + blk];
    __syncthreads();
    int base = blk * EPB;
    for (int k = 0; k < EPB / 256; ++k) {
        int t = base + k * 256 + tid;
        if (t < e) {
            int s = src[t], d = dst[t];
            int pF = atomicAdd(&cur[d >> 7], 1);
            staging[pF] = ((unsigned)(d & 127) << 16) | (unsigned)s;
            int segR = n + s;
            int pR = atomicAdd(&cur[segR >> 7], 1);
            staging[pR] = ((unsigned)(segR & 127) << 16) | (unsigned)d;
        }
    }
}

// ---------------- pass B: one block per bucket -> offs + csr
__global__ __launch_bounds__(256) void buildcsr_kernel(
    const int* __restrict__ hscan, const unsigned* __restrict__ staging,
    int* __restrict__ csr, int* __restrict__ offs,
    int n2, int e2, int nblk)
{
    __shared__ int segcnt[128];
    __shared__ int segoff[128];
    int b = blockIdx.x, tid = threadIdx.x;
    int lo = hscan[(size_t)b * nblk];
    int hi = hscan[(size_t)(b + 1) * nblk];
    if (tid < 128) segcnt[tid] = 0;
    __syncthreads();
    for (int idx = lo + tid; idx < hi; idx += 256)
        atomicAdd(&segcnt[staging[idx] >> 16], 1);
    __syncthreads();
    if (tid < 64) {
        int a = segcnt[2 * tid], c = segcnt[2 * tid + 1];
        int pair = a + c;
        int inc = pair;
        #pragma unroll
        for (int off = 1; off < 64; off <<= 1) {
            int u = __shfl_up(inc, off);
            if (tid >= off) inc += u;
        }
        int excl = inc - pair;
        segoff[2 * tid] = excl;
        segoff[2 * tid + 1] = excl + a;
    }
    __syncthreads();
    if (tid < 128) {
        int seg = (b << 7) + tid;
        if (seg < n2) offs[seg] = lo + segoff[tid];
        segcnt[tid] = segoff[tid];
    }
    if (b == gridDim.x - 1 && tid == 0) offs[n2] = e2;
    __syncthreads();
    for (int idx = lo + tid; idx < hi; idx += 256) {
        unsigned st = staging[idx];
        int pos = atomicAdd(&segcnt[st >> 16], 1);
        csr[lo + pos] = (int)(st & 0xFFFFu);
    }
}

// ---------------- gather: ONE wave per node, both directions fused.
// Scores: lane-parallel (64 edges/chunk). Accumulate: 2 edges per load instr
// (each 32-lane half owns one edge; lane loads u32 = 2 packed bf16 cols),
// 2 acc chains per direction. Halves combined at the end via shfl_xor(32).
__global__ __launch_bounds__(256) void gather_kernel(
    const int* __restrict__ offs, const int* __restrict__ csr,
    const float* __restrict__ s1, const float* __restrict__ d1,
    const float* __restrict__ s2, const float* __restrict__ d2,
    const unsigned short* __restrict__ xw1, const unsigned short* __restrict__ xw2,
    const float* __restrict__ b1, const float* __restrict__ b2,
    float* __restrict__ out, int n)
{
    int i = (blockIdx.x * 256 + threadIdx.x) >> 6;
    int lane = threadIdx.x & 63;
    if (i >= n) return;
    int half = lane >> 5;       // which edge of the pair this lane serves
    int hl = lane & 31;         // column-pair index [0,32)

    float d1i = d1[i], d2i = d2[i];
    int cF = offs[i],     endF = offs[i + 1];
    int cR = offs[n + i], endR = offs[n + i + 1];

    float mF = lrelu(s1[i] + d1i), lF = 1.0f;
    float mR = lrelu(s2[i] + d2i), lR = 1.0f;

    // self-loop seeds half 0 only (halves are partial sums, added at the end)
    unsigned suF = *(const unsigned*)(xw1 + (size_t)i * DOUT + 2 * hl);
    unsigned suR = *(const unsigned*)(xw2 + (size_t)i * DOUT + 2 * hl);
    float aFx0 = half ? 0.f : bfu_lo(suF), aFy0 = half ? 0.f : bfu_hi(suF);
    float aRx0 = half ? 0.f : bfu_lo(suR), aRy0 = half ? 0.f : bfu_hi(suR);
    float aFx1 = 0.f, aFy1 = 0.f, aRx1 = 0.f, aRy1 = 0.f;

    while (cF < endF || cR < endR) {
        int cntF = endF - cF; cntF = cntF < 0 ? 0 : (cntF > 64 ? 64 : cntF);
        int cntR = endR - cR; cntR = cntR < 0 ? 0 : (cntR > 64 ? 64 : cntR);

        int jF = 0, jR = 0;
        float scF = -1e30f, scR = -1e30f;
        if (lane < cntF) { jF = csr[cF + lane]; scF = lrelu(s1[jF] + d1i); }
        if (lane < cntR) { jR = csr[cR + lane]; scR = lrelu(s2[jR] + d2i); }

        float cmF = scF, cmR = scR;
        #pragma unroll
        for (int off = 32; off; off >>= 1) {
            cmF = fmaxf(cmF, __shfl_xor(cmF, off));
            cmR = fmaxf(cmR, __shfl_xor(cmR, off));
        }
        float mnF = fmaxf(mF, cmF), mnR = fmaxf(mR, cmR);
        float sclF = __expf(mF - mnF), sclR = __expf(mR - mnR);  // ==1.0 when m>=cm
        float pF = __expf(scF - mnF), pR = __expf(scR - mnR);    // 0 for idle lanes
        float psF = pF, psR = pR;
        #pragma unroll
        for (int off = 32; off; off >>= 1) {
            psF += __shfl_xor(psF, off);
            psR += __shfl_xor(psR, off);
        }
        lF = fmaf(lF, sclF, psF);
        lR = fmaf(lR, sclR, psR);
        aFx0 *= sclF; aFy0 *= sclF; aFx1 *= sclF; aFy1 *= sclF;
        aRx0 *= sclR; aRy0 *= sclR; aRx1 *= sclR; aRy1 *= sclR;
        mF = mnF; mR = mnR;

        int tmax = cntF > cntR ? cntF : cntR;
        for (int t = 0; t < tmax; t += 4) {
            // p past cnt is exactly 0 -> idle slots contribute nothing (j=0 row, *0)
            float pF0 = readlane_f(pF, t),     pF1 = readlane_f(pF, t + 1);
            float pF2 = readlane_f(pF, t + 2), pF3 = readlane_f(pF, t + 3);
            int   jF0 = __builtin_amdgcn_readlane(jF, t);
            int   jF1 = __builtin_amdgcn_readlane(jF, t + 1);
            int   jF2 = __builtin_amdgcn_readlane(jF, t + 2);
            int   jF3 = __builtin_amdgcn_readlane(jF, t + 3);
            float pR0 = readlane_f(pR, t),     pR1 = readlane_f(pR, t + 1);
            float pR2 = readlane_f(pR, t + 2), pR3 = readlane_f(pR, t + 3);
            int   jR0 = __builtin_amdgcn_readlane(jR, t);
            int   jR1 = __builtin_amdgcn_readlane(jR, t + 1);
            int   jR2 = __builtin_amdgcn_readlane(jR, t + 2);
            int   jR3 = __builtin_amdgcn_readlane(jR, t + 3);

            float pFa = half ? pF1 : pF0;  int jFa = half ? jF1 : jF0;
            float pFb = half ? pF3 : pF2;  int jFb = half ? jF3 : jF2;
            float pRa = half ? pR1 : pR0;  int jRa = half ? jR1 : jR0;
            float pRb = half ? pR3 : pR2;  int jRb = half ? jR3 : jR2;

            unsigned rFa = *(const unsigned*)(xw1 + (size_t)jFa * DOUT + 2 * hl);
            unsigned rFb = *(const unsigned*)(xw1 + (size_t)jFb * DOUT + 2 * hl);
            unsigned rRa = *(const unsigned*)(xw2 + (size_t)jRa * DOUT + 2 * hl);
            unsigned rRb = *(const unsigned*)(xw2 + (size_t)jRb * DOUT + 2 * hl);

            aFx0 = fmaf(pFa, bfu_lo(rFa), aFx0);
            aFy0 = fmaf(pFa, bfu_hi(rFa), aFy0);
            aFx1 = fmaf(pFb, bfu_lo(rFb), aFx1);
            aFy1 = fmaf(pFb, bfu_hi(rFb), aFy1);
            aRx0 = fmaf(pRa, bfu_lo(rRa), aRx0);
            aRy0 = fmaf(pRa, bfu_hi(rRa), aRy0);
            aRx1 = fmaf(pRb, bfu_lo(rRb), aRx1);
            aRy1 = fmaf(pRb, bfu_hi(rRb), aRy1);
        }
        cF += cntF;
        cR += cntR;
    }

    // combine the two chains, then the two halves
    float aFx = aFx0 + aFx1, aFy = aFy0 + aFy1;
    float aRx = aRx0 + aRx1, aRy = aRy0 + aRy1;
    aFx += __shfl_xor(aFx, 32); aFy += __shfl_xor(aFy, 32);
    aRx += __shfl_xor(aRx, 32); aRy += __shfl_xor(aRy, 32);

    float invF = 1.0f / (lF + 1e-16f), invR = 1.0f / (lR + 1e-16f);
    float2 bb1 = ((const float2*)b1)[hl];
    float2 bb2 = ((const float2*)b2)[hl];
    float ox = (1.0f - ALPHA) * (aFx * invF + bb1.x) + ALPHA * (aRx * invR + bb2.x);
    float oy = (1.0f - ALPHA) * (aFy * invF + bb1.y) + ALPHA * (aRy * invR + bb2.y);
    if (half == 0) {
        float2 o; o.x = ox; o.y = oy;
        *(float2*)(out + (size_t)i * DOUT + 2 * hl) = o;
    }
}

extern "C" void kernel_launch(void* const* d_in, const int* in_sizes, int n_in,
                              void* d_out, int out_size, void* d_ws, size_t ws_size,
                              hipStream_t stream) {
    const float* x   = (const float*)d_in[0];
    const int*   ei  = (const int*)d_in[1];
    const float* W1  = (const float*)d_in[2];
    const float* as1 = (const float*)d_in[3];
    const float* ad1 = (const float*)d_in[4];
    const float* b1  = (const float*)d_in[5];
    const float* W2  = (const float*)d_in[6];
    const float* as2 = (const float*)d_in[7];
    const float* ad2 = (const float*)d_in[8];
    const float* b2  = (const float*)d_in[9];
    float* out = (float*)d_out;

    int n = in_sizes[0] / DIN;   // 50000  (< 65536 for 16-bit staging pack)
    int e = in_sizes[1] / 2;     // 800000
    const int* src = ei;
    const int* dst = ei + e;
    int n2 = 2 * n;
    int e2 = 2 * e;
    int nblk = (e + EPB - 1) / EPB;              // 391 binning blocks
    int L = NBUK * nblk;                         // hist entries (~400K)
    int ntile = (L + 1023) / 1024;               // scan tiles (~392, <=1024)
    int nbuk_eff = (n2 + 127) >> 7;              // 782 non-empty buckets
    int ntiles16 = (n + 15) >> 4;                // 3125 proj tiles

    unsigned short* xw1 = (unsigned short*)d_ws;
    unsigned short* xw2 = xw1 + (size_t)n * DOUT;
    float* s1  = (float*)(xw2 + (size_t)n * DOUT);
    float* d1  = s1 + n;
    float* s2  = d1 + n;
    float* d2  = s2 + n;
    unsigned short* wf = (unsigned short*)(d2 + n);   // 32768 ushorts
    int* hist  = (int*)(wf + 32768);
    int* hscan = hist + (size_t)L;
    int* part  = hscan + (size_t)L + 1;
    int* offs  = part + 1024;
    int* csr   = offs + (size_t)n2 + 1;
    unsigned* staging = (unsigned*)(csr + (size_t)e2);

    wfrag_kernel<<<32, 64, 0, stream>>>(W1, W2, wf);
    proj_kernel<<<(ntiles16 + 3) / 4, 256, 0, stream>>>(x, wf, as1, ad1, as2, ad2,
                                                        xw1, xw2, s1, d1, s2, d2, n);

    binhist_kernel<<<nblk, 256, 0, stream>>>(src, dst, hist, e, n, nblk);
    scan_part_kernel<<<ntile, 256, 0, stream>>>(hist, part, L);
    scan_mid_kernel<<<1, 1024, 0, stream>>>(part, ntile, hscan, L, e2);
    scan_apply_kernel<<<ntile, 256, 0, stream>>>(hist, part, hscan, L);
    binscatter_kernel<<<nblk, 256, 0, stream>>>(src, dst, hscan, staging, e, n, nblk);
    buildcsr_kernel<<<nbuk_eff, 256, 0, stream>>>(hscan, staging, csr, offs, n2, e2, nblk);

    long long gthreads = (long long)n * 64;
    int gblocks = (int)((gthreads + 255) / 256);
    gather_kernel<<<gblocks, 256, 0, stream>>>(offs, csr, s1, d1, s2, d2,
                                               xw1, xw2, b1, b2, out, n);
}